// Round 4
// baseline (1873.156 us; speedup 1.0000x reference)
//
#include <hip/hip_runtime.h>
#include <hip/hip_bf16.h>
#include <cstdint>
#include <cstddef>

#define NB 16
#define NN 8192
#define NS 512
#define NK 32
#define NG (NB*NS)          // 8192 groups
#define GPB 4               // groups per pass-block
#define NBLK (NG/GPB)       // 2048
#define NPOSI 262144        // NG*NK positions

// float64 squared distance, numpy order ((dx*dx + dy*dy) + dz*dz), no contraction.
// Matches a numpy float64 golden reference bit-for-bit (all ops IEEE RN f64).
__device__ __forceinline__ double sq3d(double dx, double dy, double dz){
#pragma clang fp contract(off)
  const double a = dx*dx;
  const double b = dy*dy;
  const double c = dz*dz;
  return (a + b) + c;
}

// ---------------- FPS: one block per batch, points in registers, f64 distances ----------------
// One __syncthreads per iteration; centroid fetched from global (L2 broadcast);
// selected indices recorded in LDS and centroids written once at the end.
__global__ __launch_bounds__(1024) void k_fps(const float* __restrict__ xyz,
                                              float* __restrict__ newxyz){
  const int b = blockIdx.x;
  const int t = threadIdx.x;
  const float* __restrict__ X = xyz + (size_t)b*NN*3;
  float fx[8], fy[8], fz[8];
  double dd[8];
#pragma unroll
  for (int j=0;j<8;++j){
    const int p = t + 1024*j;
    fx[j]=X[p*3+0]; fy[j]=X[p*3+1]; fz[j]=X[p*3+2];
    dd[j]=1e10;                      // np.full(..., 1e10) in f64
  }
  __shared__ double sbd[2][16];
  __shared__ int    sbi[2][16];
  __shared__ int    sidx[NS];
  const int lane = t & 63, wid = t >> 6;
  int f = 0;
  for (int i=0;i<NS;++i){
    if (t == 0) sidx[i] = f;         // every thread holds the same f
    const float* __restrict__ P = X + 3*(size_t)f;   // block-uniform addr -> L2 broadcast
    const double cx=(double)P[0], cy=(double)P[1], cz=(double)P[2];
    double bd = -1.0; int bi = 0x7fffffff;
#pragma unroll
    for (int j=0;j<8;++j){
      const double dx=(double)fx[j]-cx, dy=(double)fy[j]-cy, dz=(double)fz[j]-cz;
      const double d = sq3d(dx,dy,dz);
      const double nd = fmin(dd[j], d);
      dd[j] = nd;
      if (nd > bd){ bd = nd; bi = t + 1024*j; }   // ascending index: keeps first max
    }
    // wave butterfly argmax (lexicographic on (-d, idx))
#pragma unroll
    for (int m=32;m>=1;m>>=1){
      const double od = __shfl_xor(bd, m);
      const int    oi = __shfl_xor(bi, m);
      if (od > bd || (od == bd && oi < bi)){ bd = od; bi = oi; }
    }
    const int par = i & 1;
    if (lane == 0){ sbd[par][wid]=bd; sbi[par][wid]=bi; }
    __syncthreads();
    // all threads redundantly reduce the 16 wave-bests: 4 chains + combine
    double bd4[4]; int bi4[4];
#pragma unroll
    for (int c=0;c<4;++c){ bd4[c]=sbd[par][c*4]; bi4[c]=sbi[par][c*4]; }
#pragma unroll
    for (int k=1;k<4;++k){
#pragma unroll
      for (int c=0;c<4;++c){
        const double dk = sbd[par][c*4+k]; const int ik = sbi[par][c*4+k];
        if (dk > bd4[c] || (dk == bd4[c] && ik < bi4[c])){ bd4[c]=dk; bi4[c]=ik; }
      }
    }
    if (bd4[1] > bd4[0] || (bd4[1]==bd4[0] && bi4[1]<bi4[0])){ bd4[0]=bd4[1]; bi4[0]=bi4[1]; }
    if (bd4[3] > bd4[2] || (bd4[3]==bd4[2] && bi4[3]<bi4[2])){ bd4[2]=bd4[3]; bi4[2]=bi4[3]; }
    if (bd4[2] > bd4[0] || (bd4[2]==bd4[0] && bi4[2]<bi4[0])){ bd4[0]=bd4[2]; bi4[0]=bi4[2]; }
    f = __builtin_amdgcn_readfirstlane(bi4[0]);
    // no second barrier: next iteration writes the OTHER parity buffer, and the
    // barrier above prevents any wave from being 2 iterations ahead.
  }
  __syncthreads();
  // flush centroids once
  if (t < NS){
    const int id = sidx[t];
    float* o = newxyz + ((size_t)b*NS + t)*3;
    o[0]=X[id*3+0]; o[1]=X[id*3+1]; o[2]=X[id*3+2];
  }
}

// ---------------- Ball query: one wave per centroid, f64 distances ----------------
__global__ __launch_bounds__(256) void k_ball(const float* __restrict__ xyz,
                                              const float* __restrict__ newxyz,
                                              int* __restrict__ idx){
  const int w = (blockIdx.x << 2) + (threadIdx.x >> 6);  // group id = b*NS+s
  const int lane = threadIdx.x & 63;
  const int b = w >> 9;
  const float* __restrict__ C = newxyz + (size_t)w*3;
  const double cx=(double)C[0], cy=(double)C[1], cz=(double)C[2];
  const float* __restrict__ X = xyz + (size_t)b*NN*3;
  int* __restrict__ out = idx + (size_t)w*NK;
  const double R2 = 0.2*0.2;   // f64: 0.04000000000000000083...
  int count = 0, first = 0;
  for (int base=0; base<NN && count<NK; base+=64){
    const int p = base + lane;
    const double d = sq3d((double)X[p*3+0]-cx, (double)X[p*3+1]-cy, (double)X[p*3+2]-cz);
    const bool q = !(d > R2);                    // include iff dist <= r^2
    const unsigned long long m = __ballot(q);
    if (q){
      const int pos = count + __popcll(m & ((1ull<<lane)-1ull));
      if (pos < NK) out[pos] = p;
    }
    if (count == 0 && m) first = base + __builtin_ctzll(m);
    count += __popcll(m);
  }
  if (lane >= count && lane < NK) out[lane] = first;   // pad with first index
}

// ---------------- per-block stats (+optional group min/max) reduction ----------------
__device__ __forceinline__ void stats_reduce(
    float v[4][8], float* __restrict__ sRed, int t, int tp, int tc, int blk,
    int chtot, int choff, bool domm,
    float* __restrict__ pS, float* __restrict__ pQ,
    float* __restrict__ mxp, float* __restrict__ mnp)
{
  __syncthreads();   // sRed overlays sX0/sW0/sV — ensure all prior reads done
  float S=0.f, Q=0.f;
  for (int m=0;m<4;++m){
#pragma unroll
    for (int i=0;i<8;++i) sRed[tp*68 + tc*8 + i] = v[m][i];
    __syncthreads();
    if (t < 64){
      float mxv = -3.402823466e38f, mnv = 3.402823466e38f;
#pragma unroll
      for (int j=0;j<32;++j){
        const float x = sRed[j*68 + t];
        S += x; Q += x*x;
        mxv = fmaxf(mxv,x); mnv = fminf(mnv,x);
      }
      if (domm){
        const int gg = blk*GPB + m;
        mxp[(size_t)gg*128 + choff + t] = mxv;
        mnp[(size_t)gg*128 + choff + t] = mnv;
      }
    }
    __syncthreads();
  }
  if (t < 64){
    pS[(size_t)blk*chtot + choff + t] = S;
    pQ[(size_t)blk*chtot + choff + t] = Q;
  }
}

// 64-deep inner product accumulate: v[m][i] += sX[pos_m][k]*sW[ch_i][k]
__device__ __forceinline__ void mm64(const float* __restrict__ sXl,
                                     const float* __restrict__ sWl,
                                     int tp, int tc, float v[4][8]){
#pragma unroll 4
  for (int k=0;k<64;++k){
    float xv[4], wv[8];
#pragma unroll
    for (int m=0;m<4;++m) xv[m] = sXl[(tp+32*m)*65 + k];
#pragma unroll
    for (int i=0;i<8;++i) wv[i] = sWl[(tc*8+i)*65 + k];
#pragma unroll
    for (int m=0;m<4;++m)
#pragma unroll
      for (int i=0;i<8;++i) v[m][i] += xv[m]*wv[i];
  }
}

// ---------------- MLP pass: recompute chain to layer DEPTH, emit stats ----------------
// smem layout (floats): [0..1023] sX0 | [1024..1599] sW0(64x9) | [1600..1983] sV |
//   sRed(32x68=2176) OVERLAYS [0..2175] (sX0,sW0,sV dead by stats time) |
//   [2176..2303] sB2 | [2304..6463] sW1(64x65) | [6464..14783] sX(128x65)
template<int DEPTH>
__global__ __launch_bounds__(256) void k_pass(
    const float* __restrict__ xyz, const float* __restrict__ points,
    const float* __restrict__ newxyz, const int* __restrict__ idx,
    const float* __restrict__ w0, const float* __restrict__ b0,
    const float* __restrict__ w1, const float* __restrict__ b1,
    const float* __restrict__ w2, const float* __restrict__ b2,
    const float* __restrict__ ac,
    float* __restrict__ pS, float* __restrict__ pQ,
    float* __restrict__ mxp, float* __restrict__ mnp)
{
  __shared__ float smem[(DEPTH>=1) ? 14784 : 2304];
  float* sX0 = smem;
  float* sW0 = smem + 1024;
  float* sV  = smem + 1600;
  float* sRed= smem;            // overlay
  float* sB2 = smem + 2176;
  float* sW1 = smem + 2304;
  float* sX  = smem + 6464;

  const int t = threadIdx.x;
  const int blk = blockIdx.x;
  const int tc = t & 7, tp = t >> 3;

  // stage weights / params
  for (int i=t;i<384;i+=256) sW0[(i/6)*9 + (i%6)] = w0[i];
  if (t < 64) sV[t] = b0[t];
  if constexpr (DEPTH >= 1){
    if (t < 64){ sV[64+t]=ac[t]; sV[128+t]=ac[64+t]; sV[192+t]=b1[t]; }
    for (int i=t;i<4096;i+=256) sW1[(i>>6)*65 + (i&63)] = w1[i];
  }
  if constexpr (DEPTH == 2){
    if (t < 64){ sV[256+t]=ac[128+t]; sV[320+t]=ac[192+t]; }
    if (t < 128) sB2[t] = b2[t];
  }

  // gather -> x0 (6 ch): [gxyz - centroid, gpts]
  {
    const int pos = t & 127;
    const int gg = blk*GPB + (pos >> 5);
    const int b  = gg >> 9;
    const int id = idx[gg*NK + (pos & 31)];
    if (t < 128){
      const float* __restrict__ P = xyz + ((size_t)b*NN + id)*3;
      const float* __restrict__ C = newxyz + (size_t)gg*3;
      sX0[pos*8+0] = P[0]-C[0];
      sX0[pos*8+1] = P[1]-C[1];
      sX0[pos*8+2] = P[2]-C[2];
    } else {
      const float* __restrict__ P = points + ((size_t)b*NN + id)*3;
      sX0[pos*8+3] = P[0];
      sX0[pos*8+4] = P[1];
      sX0[pos*8+5] = P[2];
    }
  }
  __syncthreads();

  // y0 = W0 x0 + b0   (thread: 4 positions x 8 channels)
  float v[4][8];
#pragma unroll
  for (int m=0;m<4;++m){
    const int pos = tp + 32*m;
    float xr[6];
#pragma unroll
    for (int c=0;c<6;++c) xr[c] = sX0[pos*8+c];
#pragma unroll
    for (int i=0;i<8;++i){
      const int ch = tc*8+i;
      float acc = sV[ch];
#pragma unroll
      for (int c=0;c<6;++c) acc += sW0[ch*9+c]*xr[c];
      v[m][i] = acc;
    }
  }

  if constexpr (DEPTH == 0){
    stats_reduce(v, sRed, t, tp, tc, blk, 64, 0, false, pS, pQ, mxp, mnp);
    return;
  } else {
    // x1 = relu(a0*y0 + c0)
#pragma unroll
    for (int m=0;m<4;++m){
      const int pos = tp + 32*m;
#pragma unroll
      for (int i=0;i<8;++i){
        const int ch = tc*8+i;
        sX[pos*65+ch] = fmaxf(sV[64+ch]*v[m][i] + sV[128+ch], 0.f);
      }
    }
    __syncthreads();
    // y1 = W1 x1 + b1
#pragma unroll
    for (int m=0;m<4;++m)
#pragma unroll
      for (int i=0;i<8;++i) v[m][i] = sV[192 + tc*8 + i];
    mm64(sX, sW1, tp, tc, v);

    if constexpr (DEPTH == 1){
      stats_reduce(v, sRed, t, tp, tc, blk, 64, 0, false, pS, pQ, mxp, mnp);
      return;
    } else {
      __syncthreads();
      // x2 = relu(a1*y1 + c1), overwrite sX
#pragma unroll
      for (int m=0;m<4;++m){
        const int pos = tp + 32*m;
#pragma unroll
        for (int i=0;i<8;++i){
          const int ch = tc*8+i;
          sX[pos*65+ch] = fmaxf(sV[256+ch]*v[m][i] + sV[320+ch], 0.f);
        }
      }
      __syncthreads();
      // y2 = W2 x2 + b2 in two 64-channel chunks (W2 chunk reuses sW1 space)
      for (int o=0;o<2;++o){
        for (int i=t;i<4096;i+=256) sW1[(i>>6)*65 + (i&63)] = w2[o*4096 + i];
        __syncthreads();
#pragma unroll
        for (int m=0;m<4;++m)
#pragma unroll
          for (int i=0;i<8;++i) v[m][i] = sB2[o*64 + tc*8 + i];
        mm64(sX, sW1, tp, tc, v);
        stats_reduce(v, sRed, t, tp, tc, blk, 128, o*64, true, pS, pQ, mxp, mnp);
      }
      return;
    }
  }
}

// ---------------- derive BN affine a,c from partial sums (deterministic) ----------------
__global__ __launch_bounds__(128) void k_stats(const float* __restrict__ pS, const float* __restrict__ pQ,
                                               const float* __restrict__ g, const float* __restrict__ beta,
                                               float* __restrict__ a, float* __restrict__ c, int CH){
  const int ch = threadIdx.x;
  if (ch >= CH) return;
  float S=0.f, Q=0.f;
#pragma unroll 8
  for (int j=0;j<NBLK;++j){ S += pS[(size_t)j*CH + ch]; Q += pQ[(size_t)j*CH + ch]; }
  const float mean = S * (1.f/(float)NPOSI);
  const float var  = fmaxf(Q * (1.f/(float)NPOSI) - mean*mean, 0.f);
  const float av = g[ch] * rsqrtf(var + 1e-5f);
  a[ch] = av;
  c[ch] = beta[ch] - mean*av;
}

// ---------------- final: BN+ReLU applied to pooled value ----------------
__global__ __launch_bounds__(256) void k_final(const float* __restrict__ mxp, const float* __restrict__ mnp,
                                               const float* __restrict__ a, const float* __restrict__ c,
                                               float* __restrict__ out){
  const int i = blockIdx.x*256 + threadIdx.x;
  const int ch = i & 127;
  const float av = a[ch], cv = c[ch];
  const float vv = (av >= 0.f) ? mxp[i] : mnp[i];   // relu∘affine is monotone
  out[i] = fmaxf(av*vv + cv, 0.f);
}

extern "C" void kernel_launch(void* const* d_in, const int* in_sizes, int n_in,
                              void* d_out, int out_size, void* d_ws, size_t ws_size,
                              hipStream_t stream){
  (void)in_sizes; (void)n_in; (void)out_size;
  const float* xyz    = (const float*)d_in[0];
  const float* points = (const float*)d_in[1];
  const float* w0 = (const float*)d_in[2];
  const float* b0 = (const float*)d_in[3];
  const float* g0 = (const float*)d_in[4];
  const float* be0= (const float*)d_in[5];
  const float* w1 = (const float*)d_in[6];
  const float* b1 = (const float*)d_in[7];
  const float* g1 = (const float*)d_in[8];
  const float* be1= (const float*)d_in[9];
  const float* w2 = (const float*)d_in[10];
  const float* b2 = (const float*)d_in[11];
  const float* g2 = (const float*)d_in[12];
  const float* be2= (const float*)d_in[13];

  float* out_newxyz = (float*)d_out;
  float* out_newpts = out_newxyz + (size_t)NB*NS*3;

  char* ws = (char*)d_ws;
  int*   idx = (int*)ws;                              // 1 MiB
  float* ac  = (float*)(ws + (1u<<20));               // 512 floats (a0,c0,a1,c1,a2,c2)
  float* pS  = (float*)(ws + (1u<<20) + 4096);        // 2048*128 f
  float* pQ  = pS + (size_t)NBLK*128;                 // 2048*128 f
  float* mxp = pQ + (size_t)NBLK*128;                 // 8192*128 f
  float* mnp = mxp + (size_t)NG*128;                  // 8192*128 f
  const size_t need = (1u<<20) + 4096 + (size_t)2*NBLK*128*4 + (size_t)2*NG*128*4;
  if (ws_size < need) return;  // ~11.5 MiB required

  k_fps <<<NB, 1024, 0, stream>>>(xyz, out_newxyz);
  k_ball<<<NG/4, 256, 0, stream>>>(xyz, out_newxyz, idx);

  k_pass<0><<<NBLK,256,0,stream>>>(xyz,points,out_newxyz,idx,w0,b0,w1,b1,w2,b2,ac,pS,pQ,mxp,mnp);
  k_stats<<<1,128,0,stream>>>(pS,pQ,g0,be0, ac+0,   ac+64,  64);
  k_pass<1><<<NBLK,256,0,stream>>>(xyz,points,out_newxyz,idx,w0,b0,w1,b1,w2,b2,ac,pS,pQ,mxp,mnp);
  k_stats<<<1,128,0,stream>>>(pS,pQ,g1,be1, ac+128, ac+192, 64);
  k_pass<2><<<NBLK,256,0,stream>>>(xyz,points,out_newxyz,idx,w0,b0,w1,b1,w2,b2,ac,pS,pQ,mxp,mnp);
  k_stats<<<1,128,0,stream>>>(pS,pQ,g2,be2, ac+256, ac+384, 128);
  k_final<<<(NG*128)/256,256,0,stream>>>(mxp,mnp,ac+256,ac+384,out_newpts);
}

// Round 5
// 1415.059 us; speedup vs baseline: 1.3237x; 1.3237x over previous
//
#include <hip/hip_runtime.h>
#include <hip/hip_bf16.h>
#include <cstdint>
#include <cstddef>

#define NB 16
#define NN 8192
#define NS 512
#define NK 32
#define NG (NB*NS)          // 8192 groups
#define GPB 4               // groups per pass-block
#define NBLK (NG/GPB)       // 2048
#define NPOSI 262144        // NG*NK positions

// float64 squared distance, numpy order ((dx*dx + dy*dy) + dz*dz), no contraction.
// Matches a numpy float64 golden reference bit-for-bit (all ops IEEE RN f64).
__device__ __forceinline__ double sq3d(double dx, double dy, double dz){
#pragma clang fp contract(off)
  const double a = dx*dx;
  const double b = dy*dy;
  const double c = dz*dz;
  return (a + b) + c;
}

// ---------------- FPS: f32 screen + exact f64 fallback ----------------
// dd64 is the canonical numpy-f64 min-distance array. A cheap f32 distance
// decides "no update possible" conservatively: if d64 < dd64 then
// d32 <= dd32*(1+2^-19) (error budget ~2^-21.7), so skipping when
// d32 > dd32 + dd32*2^-19 never misses an update. Argmax = block max of dd64
// (u64-bit atomicMax of nonneg doubles) + exact equality scan + atomicMin idx
// (= first-index semantics).
__global__ __launch_bounds__(1024) void k_fps(const float* __restrict__ xyz,
                                              float* __restrict__ newxyz){
  const int b = blockIdx.x;
  const int t = threadIdx.x;
  const float* __restrict__ X = xyz + (size_t)b*NN*3;
  float px[8], py[8], pz[8], dd32[8];
  double dd[8];
#pragma unroll
  for (int j=0;j<8;++j){
    const int p = t + 1024*j;
    px[j]=X[p*3+0]; py[j]=X[p*3+1]; pz[j]=X[p*3+2];
    dd[j]=1e10; dd32[j]=1e10f;
  }
  __shared__ unsigned long long sMax[2];
  __shared__ int sIdx[2];
  __shared__ int sSel[NS];
  if (t < 2){ sMax[t]=0ull; sIdx[t]=0x7fffffff; }
  __syncthreads();
  int f = 0;
  for (int i=0;i<NS;++i){
    if (t == 0) sSel[i] = f;
    if (i == NS-1) break;                       // last argmax is unused
    const int par = i & 1;
    // ---- Phase A: screen + update + value reduce ----
    const float* __restrict__ P = X + 3*(size_t)f;   // uniform addr -> L2
    const float cx32=P[0], cy32=P[1], cz32=P[2];
    const double cx=(double)cx32, cy=(double)cy32, cz=(double)cz32;
    double bd = -1.0;
#pragma unroll
    for (int j=0;j<8;++j){
      const float ax=px[j]-cx32, ay=py[j]-cy32, az=pz[j]-cz32;
      const float d32 = ax*ax + ay*ay + az*az;       // any rounding: screen only
      const float thr = fmaf(dd32[j], 0x1p-19f, dd32[j]);
      if (d32 <= thr){                               // possible update: exact path
        const double d = sq3d((double)px[j]-cx, (double)py[j]-cy, (double)pz[j]-cz);
        const double nd = fmin(dd[j], d);
        dd[j] = nd; dd32[j] = (float)nd;
      }
      bd = fmax(bd, dd[j]);
    }
#pragma unroll
    for (int m=32;m>=1;m>>=1)
      bd = fmax(bd, __shfl_xor(bd, m));
    if ((t & 63) == 0)
      atomicMax(&sMax[par], (unsigned long long)__double_as_longlong(bd));
    __syncthreads();   // barrier 1: block max ready
    // ---- Phase B: exact argmax via equality scan + atomicMin ----
    const double bmax = __longlong_as_double((long long)sMax[par]);
    int cand = 0x7fffffff;
#pragma unroll
    for (int j=7;j>=0;--j)
      if (dd[j] == bmax) cand = t + 1024*j;          // descending -> min j kept
    if (cand != 0x7fffffff) atomicMin(&sIdx[par], cand);
    if (t == 0){ sMax[par^1]=0ull; sIdx[par^1]=0x7fffffff; }  // reset other slot
    __syncthreads();   // barrier 2: index ready, resets ordered vs next writers
    f = sIdx[par];
  }
  __syncthreads();
  // flush centroids once
  if (t < NS){
    const int id = sSel[t];
    float* o = newxyz + ((size_t)b*NS + t)*3;
    o[0]=X[id*3+0]; o[1]=X[id*3+1]; o[2]=X[id*3+2];
  }
}

// ---------------- Ball query: one wave per centroid, f64 distances ----------------
__global__ __launch_bounds__(256) void k_ball(const float* __restrict__ xyz,
                                              const float* __restrict__ newxyz,
                                              int* __restrict__ idx){
  const int w = (blockIdx.x << 2) + (threadIdx.x >> 6);  // group id = b*NS+s
  const int lane = threadIdx.x & 63;
  const int b = w >> 9;
  const float* __restrict__ C = newxyz + (size_t)w*3;
  const double cx=(double)C[0], cy=(double)C[1], cz=(double)C[2];
  const float* __restrict__ X = xyz + (size_t)b*NN*3;
  int* __restrict__ out = idx + (size_t)w*NK;
  const double R2 = 0.2*0.2;   // f64: 0.04000000000000000083...
  int count = 0, first = 0;
  for (int base=0; base<NN && count<NK; base+=64){
    const int p = base + lane;
    const double d = sq3d((double)X[p*3+0]-cx, (double)X[p*3+1]-cy, (double)X[p*3+2]-cz);
    const bool q = !(d > R2);                    // include iff dist <= r^2
    const unsigned long long m = __ballot(q);
    if (q){
      const int pos = count + __popcll(m & ((1ull<<lane)-1ull));
      if (pos < NK) out[pos] = p;
    }
    if (count == 0 && m) first = base + __builtin_ctzll(m);
    count += __popcll(m);
  }
  if (lane >= count && lane < NK) out[lane] = first;   // pad with first index
}

// ---------------- per-block stats (+optional group min/max) reduction ----------------
__device__ __forceinline__ void stats_reduce(
    float v[4][8], float* __restrict__ sRed, int t, int tp, int tc, int blk,
    int chtot, int choff, bool domm,
    float* __restrict__ pS, float* __restrict__ pQ,
    float* __restrict__ mxp, float* __restrict__ mnp)
{
  __syncthreads();   // sRed overlays sX0/sW0/sV — ensure all prior reads done
  float S=0.f, Q=0.f;
  for (int m=0;m<4;++m){
#pragma unroll
    for (int i=0;i<8;++i) sRed[tp*68 + tc*8 + i] = v[m][i];
    __syncthreads();
    if (t < 64){
      float mxv = -3.402823466e38f, mnv = 3.402823466e38f;
#pragma unroll
      for (int j=0;j<32;++j){
        const float x = sRed[j*68 + t];
        S += x; Q += x*x;
        mxv = fmaxf(mxv,x); mnv = fminf(mnv,x);
      }
      if (domm){
        const int gg = blk*GPB + m;
        mxp[(size_t)gg*128 + choff + t] = mxv;
        mnp[(size_t)gg*128 + choff + t] = mnv;
      }
    }
    __syncthreads();
  }
  if (t < 64){
    pS[(size_t)blk*chtot + choff + t] = S;
    pQ[(size_t)blk*chtot + choff + t] = Q;
  }
}

// 64-deep inner product accumulate: v[m][i] += sX[pos_m][k]*sW[ch_i][k]
__device__ __forceinline__ void mm64(const float* __restrict__ sXl,
                                     const float* __restrict__ sWl,
                                     int tp, int tc, float v[4][8]){
#pragma unroll 4
  for (int k=0;k<64;++k){
    float xv[4], wv[8];
#pragma unroll
    for (int m=0;m<4;++m) xv[m] = sXl[(tp+32*m)*65 + k];
#pragma unroll
    for (int i=0;i<8;++i) wv[i] = sWl[(tc*8+i)*65 + k];
#pragma unroll
    for (int m=0;m<4;++m)
#pragma unroll
      for (int i=0;i<8;++i) v[m][i] += xv[m]*wv[i];
  }
}

// ---------------- MLP pass: recompute chain to layer DEPTH, emit stats ----------------
// smem layout (floats): [0..1023] sX0 | [1024..1599] sW0(64x9) | [1600..1983] sV |
//   sRed(32x68=2176) OVERLAYS [0..2175] (sX0,sW0,sV dead by stats time) |
//   [2176..2303] sB2 | [2304..6463] sW1(64x65) | [6464..14783] sX(128x65)
template<int DEPTH>
__global__ __launch_bounds__(256) void k_pass(
    const float* __restrict__ xyz, const float* __restrict__ points,
    const float* __restrict__ newxyz, const int* __restrict__ idx,
    const float* __restrict__ w0, const float* __restrict__ b0,
    const float* __restrict__ w1, const float* __restrict__ b1,
    const float* __restrict__ w2, const float* __restrict__ b2,
    const float* __restrict__ ac,
    float* __restrict__ pS, float* __restrict__ pQ,
    float* __restrict__ mxp, float* __restrict__ mnp)
{
  __shared__ float smem[(DEPTH>=1) ? 14784 : 2304];
  float* sX0 = smem;
  float* sW0 = smem + 1024;
  float* sV  = smem + 1600;
  float* sRed= smem;            // overlay
  float* sB2 = smem + 2176;
  float* sW1 = smem + 2304;
  float* sX  = smem + 6464;

  const int t = threadIdx.x;
  const int blk = blockIdx.x;
  const int tc = t & 7, tp = t >> 3;

  // stage weights / params
  for (int i=t;i<384;i+=256) sW0[(i/6)*9 + (i%6)] = w0[i];
  if (t < 64) sV[t] = b0[t];
  if constexpr (DEPTH >= 1){
    if (t < 64){ sV[64+t]=ac[t]; sV[128+t]=ac[64+t]; sV[192+t]=b1[t]; }
    for (int i=t;i<4096;i+=256) sW1[(i>>6)*65 + (i&63)] = w1[i];
  }
  if constexpr (DEPTH == 2){
    if (t < 64){ sV[256+t]=ac[128+t]; sV[320+t]=ac[192+t]; }
    if (t < 128) sB2[t] = b2[t];
  }

  // gather -> x0 (6 ch): [gxyz - centroid, gpts]
  {
    const int pos = t & 127;
    const int gg = blk*GPB + (pos >> 5);
    const int b  = gg >> 9;
    const int id = idx[gg*NK + (pos & 31)];
    if (t < 128){
      const float* __restrict__ P = xyz + ((size_t)b*NN + id)*3;
      const float* __restrict__ C = newxyz + (size_t)gg*3;
      sX0[pos*8+0] = P[0]-C[0];
      sX0[pos*8+1] = P[1]-C[1];
      sX0[pos*8+2] = P[2]-C[2];
    } else {
      const float* __restrict__ P = points + ((size_t)b*NN + id)*3;
      sX0[pos*8+3] = P[0];
      sX0[pos*8+4] = P[1];
      sX0[pos*8+5] = P[2];
    }
  }
  __syncthreads();

  // y0 = W0 x0 + b0   (thread: 4 positions x 8 channels)
  float v[4][8];
#pragma unroll
  for (int m=0;m<4;++m){
    const int pos = tp + 32*m;
    float xr[6];
#pragma unroll
    for (int c=0;c<6;++c) xr[c] = sX0[pos*8+c];
#pragma unroll
    for (int i=0;i<8;++i){
      const int ch = tc*8+i;
      float acc = sV[ch];
#pragma unroll
      for (int c=0;c<6;++c) acc += sW0[ch*9+c]*xr[c];
      v[m][i] = acc;
    }
  }

  if constexpr (DEPTH == 0){
    stats_reduce(v, sRed, t, tp, tc, blk, 64, 0, false, pS, pQ, mxp, mnp);
    return;
  } else {
    // x1 = relu(a0*y0 + c0)
#pragma unroll
    for (int m=0;m<4;++m){
      const int pos = tp + 32*m;
#pragma unroll
      for (int i=0;i<8;++i){
        const int ch = tc*8+i;
        sX[pos*65+ch] = fmaxf(sV[64+ch]*v[m][i] + sV[128+ch], 0.f);
      }
    }
    __syncthreads();
    // y1 = W1 x1 + b1
#pragma unroll
    for (int m=0;m<4;++m)
#pragma unroll
      for (int i=0;i<8;++i) v[m][i] = sV[192 + tc*8 + i];
    mm64(sX, sW1, tp, tc, v);

    if constexpr (DEPTH == 1){
      stats_reduce(v, sRed, t, tp, tc, blk, 64, 0, false, pS, pQ, mxp, mnp);
      return;
    } else {
      __syncthreads();
      // x2 = relu(a1*y1 + c1), overwrite sX
#pragma unroll
      for (int m=0;m<4;++m){
        const int pos = tp + 32*m;
#pragma unroll
        for (int i=0;i<8;++i){
          const int ch = tc*8+i;
          sX[pos*65+ch] = fmaxf(sV[256+ch]*v[m][i] + sV[320+ch], 0.f);
        }
      }
      __syncthreads();
      // y2 = W2 x2 + b2 in two 64-channel chunks (W2 chunk reuses sW1 space)
      for (int o=0;o<2;++o){
        for (int i=t;i<4096;i+=256) sW1[(i>>6)*65 + (i&63)] = w2[o*4096 + i];
        __syncthreads();
#pragma unroll
        for (int m=0;m<4;++m)
#pragma unroll
          for (int i=0;i<8;++i) v[m][i] = sB2[o*64 + tc*8 + i];
        mm64(sX, sW1, tp, tc, v);
        stats_reduce(v, sRed, t, tp, tc, blk, 128, o*64, true, pS, pQ, mxp, mnp);
      }
      return;
    }
  }
}

// ---------------- derive BN affine a,c from partial sums (deterministic) ----------------
__global__ __launch_bounds__(128) void k_stats(const float* __restrict__ pS, const float* __restrict__ pQ,
                                               const float* __restrict__ g, const float* __restrict__ beta,
                                               float* __restrict__ a, float* __restrict__ c, int CH){
  const int ch = threadIdx.x;
  if (ch >= CH) return;
  float S=0.f, Q=0.f;
#pragma unroll 8
  for (int j=0;j<NBLK;++j){ S += pS[(size_t)j*CH + ch]; Q += pQ[(size_t)j*CH + ch]; }
  const float mean = S * (1.f/(float)NPOSI);
  const float var  = fmaxf(Q * (1.f/(float)NPOSI) - mean*mean, 0.f);
  const float av = g[ch] * rsqrtf(var + 1e-5f);
  a[ch] = av;
  c[ch] = beta[ch] - mean*av;
}

// ---------------- final: BN+ReLU applied to pooled value ----------------
__global__ __launch_bounds__(256) void k_final(const float* __restrict__ mxp, const float* __restrict__ mnp,
                                               const float* __restrict__ a, const float* __restrict__ c,
                                               float* __restrict__ out){
  const int i = blockIdx.x*256 + threadIdx.x;
  const int ch = i & 127;
  const float av = a[ch], cv = c[ch];
  const float vv = (av >= 0.f) ? mxp[i] : mnp[i];   // relu∘affine is monotone
  out[i] = fmaxf(av*vv + cv, 0.f);
}

extern "C" void kernel_launch(void* const* d_in, const int* in_sizes, int n_in,
                              void* d_out, int out_size, void* d_ws, size_t ws_size,
                              hipStream_t stream){
  (void)in_sizes; (void)n_in; (void)out_size;
  const float* xyz    = (const float*)d_in[0];
  const float* points = (const float*)d_in[1];
  const float* w0 = (const float*)d_in[2];
  const float* b0 = (const float*)d_in[3];
  const float* g0 = (const float*)d_in[4];
  const float* be0= (const float*)d_in[5];
  const float* w1 = (const float*)d_in[6];
  const float* b1 = (const float*)d_in[7];
  const float* g1 = (const float*)d_in[8];
  const float* be1= (const float*)d_in[9];
  const float* w2 = (const float*)d_in[10];
  const float* b2 = (const float*)d_in[11];
  const float* g2 = (const float*)d_in[12];
  const float* be2= (const float*)d_in[13];

  float* out_newxyz = (float*)d_out;
  float* out_newpts = out_newxyz + (size_t)NB*NS*3;

  char* ws = (char*)d_ws;
  int*   idx = (int*)ws;                              // 1 MiB
  float* ac  = (float*)(ws + (1u<<20));               // 512 floats (a0,c0,a1,c1,a2,c2)
  float* pS  = (float*)(ws + (1u<<20) + 4096);        // 2048*128 f
  float* pQ  = pS + (size_t)NBLK*128;                 // 2048*128 f
  float* mxp = pQ + (size_t)NBLK*128;                 // 8192*128 f
  float* mnp = mxp + (size_t)NG*128;                  // 8192*128 f
  const size_t need = (1u<<20) + 4096 + (size_t)2*NBLK*128*4 + (size_t)2*NG*128*4;
  if (ws_size < need) return;  // ~11.5 MiB required

  k_fps <<<NB, 1024, 0, stream>>>(xyz, out_newxyz);
  k_ball<<<NG/4, 256, 0, stream>>>(xyz, out_newxyz, idx);

  k_pass<0><<<NBLK,256,0,stream>>>(xyz,points,out_newxyz,idx,w0,b0,w1,b1,w2,b2,ac,pS,pQ,mxp,mnp);
  k_stats<<<1,128,0,stream>>>(pS,pQ,g0,be0, ac+0,   ac+64,  64);
  k_pass<1><<<NBLK,256,0,stream>>>(xyz,points,out_newxyz,idx,w0,b0,w1,b1,w2,b2,ac,pS,pQ,mxp,mnp);
  k_stats<<<1,128,0,stream>>>(pS,pQ,g1,be1, ac+128, ac+192, 64);
  k_pass<2><<<NBLK,256,0,stream>>>(xyz,points,out_newxyz,idx,w0,b0,w1,b1,w2,b2,ac,pS,pQ,mxp,mnp);
  k_stats<<<1,128,0,stream>>>(pS,pQ,g2,be2, ac+256, ac+384, 128);
  k_final<<<(NG*128)/256,256,0,stream>>>(mxp,mnp,ac+256,ac+384,out_newpts);
}